// Round 7
// baseline (629.612 us; speedup 1.0000x reference)
//
#include <hip/hip_runtime.h>

// GraphSAGE 3-layer. Round 7: GEMM staging via global_load_lds (16B) +
// 2-phase double-buffered prefetch.
//   - LDS kept LINEAR (slot = tid*16B -> wave-uniform base + lane*16, the
//     global_load_lds constraint); XOR swizzle applied to the GLOBAL source
//     col-group (kseg^(row&7)) and to the ds_read address (same involution).
//   - stage(next buf) issued BEFORE ds_read+MFMA of current buf; the
//     __syncthreads() at step end drains the prefetch (flew under MFMA).
//   - OOB A-rows clamp to row 0 (their outputs are discarded).
//   - CSR gather aggregation; bf16 activations; bucketed CSR fill (round 6);
//     layer 2 transform-before-aggregate (64-wide gather).

constexpr int NN = 100000;
constexpr int NE = 1600000;

typedef short s16x8 __attribute__((ext_vector_type(8)));
typedef float f32x4 __attribute__((ext_vector_type(4)));

struct ushort4_t { unsigned short x, y, z, w; };
struct ushort2_t { unsigned short x, y; };

__device__ __forceinline__ float bf2f(unsigned short u) {
    union { unsigned int i; float f; } c; c.i = ((unsigned int)u) << 16; return c.f;
}
__device__ __forceinline__ unsigned short f2bf(float f) {
    union { float f; unsigned int i; } c; c.f = f;
    unsigned int r = (c.i + 0x7fffu + ((c.i >> 16) & 1u)) >> 16;
    return (unsigned short)r;
}

__device__ __forceinline__ void gl16(const void* g, void* l) {
    __builtin_amdgcn_global_load_lds(
        (const __attribute__((address_space(1))) unsigned int*)g,
        (__attribute__((address_space(3))) unsigned int*)l, 16, 0, 0);
}

// ---------------- CSR build ----------------
__global__ void deg_hist_kernel(const int* __restrict__ dst, int* __restrict__ degi, int n) {
    int e = blockIdx.x * blockDim.x + threadIdx.x;
    if (e < n) atomicAdd(&degi[dst[e]], 1);
}

constexpr int SCHUNK = 1024;
constexpr int NCH = (NN + SCHUNK - 1) / SCHUNK;   // 98
constexpr int NB = (NN + 255) / 256;              // 391

__global__ void chunk_sum_kernel(const int* __restrict__ degi, int* __restrict__ csum) {
    __shared__ int red[256];
    const int blk = blockIdx.x, t = threadIdx.x;
    const int base = blk * SCHUNK + t * 4;
    int s = 0;
#pragma unroll
    for (int u = 0; u < 4; ++u) { const int i = base + u; if (i < NN) s += degi[i]; }
    red[t] = s;
    __syncthreads();
    for (int o = 128; o > 0; o >>= 1) {
        if (t < o) red[t] += red[t + o];
        __syncthreads();
    }
    if (t == 0) csum[blk] = red[0];
}

__global__ void chunk_scan_kernel(const int* __restrict__ csum, int* __restrict__ coff,
                                  int* __restrict__ row_start) {
    __shared__ int sh[128];
    const int t = threadIdx.x;
    const int v0 = (t < NCH) ? csum[t] : 0;
    sh[t] = v0;
    __syncthreads();
    for (int o = 1; o < 128; o <<= 1) {
        const int v = (t >= o) ? sh[t - o] : 0;
        __syncthreads();
        sh[t] += v;
        __syncthreads();
    }
    if (t < NCH) coff[t] = sh[t] - v0;   // exclusive
    if (t == 0) row_start[NN] = NE;
}

__global__ void scan_write_kernel(const int* __restrict__ degi, const int* __restrict__ coff,
                                  int* __restrict__ row_start, int* __restrict__ gcur,
                                  float* __restrict__ rdeg) {
    __shared__ int sh[256];
    const int blk = blockIdx.x, t = threadIdx.x;
    const int base = blk * SCHUNK + t * 4;
    int d[4]; int s = 0;
#pragma unroll
    for (int u = 0; u < 4; ++u) { const int i = base + u; d[u] = (i < NN) ? degi[i] : 0; s += d[u]; }
    sh[t] = s;
    __syncthreads();
    for (int o = 1; o < 256; o <<= 1) {
        const int v = (t >= o) ? sh[t - o] : 0;
        __syncthreads();
        sh[t] += v;
        __syncthreads();
    }
    int run = coff[blk] + sh[t] - s;
#pragma unroll
    for (int u = 0; u < 4; ++u) {
        const int i = base + u;
        if (i < NN) {
            row_start[i] = run;
            if ((i & 255) == 0) gcur[i >> 8] = run;
            rdeg[i] = 1.0f / (float)max(d[u], 1);
            run += d[u];
        }
    }
}

constexpr int EPB_A = 4096;
__global__ __launch_bounds__(256) void bucket_scatter_kernel(
    const int* __restrict__ src, const int* __restrict__ dst,
    int* __restrict__ gcur, int2* __restrict__ ebuf) {
    __shared__ int hist[NB];
    __shared__ int base[NB];
    const int blk = blockIdx.x, t = threadIdx.x;
    int myS[16], myD[16];
#pragma unroll
    for (int u = 0; u < 16; ++u) {
        const int i = blk * EPB_A + u * 256 + t;
        if (i < NE) { myS[u] = src[i]; myD[u] = dst[i]; } else myD[u] = -1;
    }
    for (int b = t; b < NB; b += 256) hist[b] = 0;
    __syncthreads();
#pragma unroll
    for (int u = 0; u < 16; ++u)
        if (myD[u] >= 0) atomicAdd(&hist[myD[u] >> 8], 1);
    __syncthreads();
    for (int b = t; b < NB; b += 256) {
        const int c = hist[b];
        base[b] = c ? atomicAdd(&gcur[b], c) : 0;
    }
    __syncthreads();
    for (int b = t; b < NB; b += 256) hist[b] = 0;
    __syncthreads();
#pragma unroll
    for (int u = 0; u < 16; ++u)
        if (myD[u] >= 0) {
            const int bk = myD[u] >> 8;
            const int off = atomicAdd(&hist[bk], 1);
            ebuf[base[bk] + off] = make_int2(myS[u], myD[u]);
        }
}

__global__ __launch_bounds__(256) void bucket_fill_kernel(
    const int2* __restrict__ ebuf, const int* __restrict__ row_start,
    int* __restrict__ csr) {
    __shared__ int lcur[256];
    const int b = blockIdx.x, t = threadIdx.x;
    const int nbase = b << 8;
    const int nend = min(nbase + 256, NN);
    if (nbase + t < nend) lcur[t] = row_start[nbase + t];
    __syncthreads();
    const int beg = row_start[nbase];
    const int end = row_start[nend];
    for (int i = beg + t; i < end; i += 256) {
        const int2 e = ebuf[i];
        const int p = atomicAdd(&lcur[e.y & 255], 1);
        csr[p] = e.x;
    }
}

// ---------------- fp32 -> bf16 converts ----------------
__global__ void cvt_f32_bf16(const float* __restrict__ src, unsigned short* __restrict__ dst, int nquad) {
    int i = blockIdx.x * blockDim.x + threadIdx.x;
    if (i >= nquad) return;
    const float4 v = reinterpret_cast<const float4*>(src)[i];
    ushort4_t o = { f2bf(v.x), f2bf(v.y), f2bf(v.z), f2bf(v.w) };
    reinterpret_cast<ushort4_t*>(dst)[i] = o;
}

__global__ void cvt_weights(const float* a, const float* b, const float* c,
                            const float* d, const float* e, const float* f,
                            unsigned short* __restrict__ o) {
    int i = blockIdx.x * blockDim.x + threadIdx.x;
    int q = i * 4;
    if (q >= 229376) return;
    const float* s; int off;
    if      (q <  32768) { s = a; off = 0; }
    else if (q <  65536) { s = b; off = 32768; }
    else if (q < 131072) { s = c; off = 65536; }
    else if (q < 196608) { s = d; off = 131072; }
    else if (q < 212992) { s = e; off = 196608; }
    else                 { s = f; off = 212992; }
    const float4 v = *reinterpret_cast<const float4*>(s + (q - off));
    ushort4_t ov = { f2bf(v.x), f2bf(v.y), f2bf(v.z), f2bf(v.w) };
    *reinterpret_cast<ushort4_t*>(o + q) = ov;
}

// ---------------- gather-mean (bf16 rows, fp32 accum, bf16 out) ----------------
template<int D>
__global__ __launch_bounds__(256) void gather_mean_bf16(
    const unsigned short* __restrict__ rows, const int* __restrict__ row_start,
    const int* __restrict__ csr, const float* __restrict__ rdeg,
    unsigned short* __restrict__ out) {
    constexpr int VPL = D / 64;
    const int node = (int)((blockIdx.x * (unsigned)blockDim.x + threadIdx.x) >> 6);
    if (node >= NN) return;
    const int lane = threadIdx.x & 63;
    const int beg = row_start[node];
    const int end = row_start[node + 1];
    float acc[VPL];
#pragma unroll
    for (int u = 0; u < VPL; ++u) acc[u] = 0.f;

    auto accum = [&](int s) {
        const unsigned short* p = rows + (size_t)s * D + lane * VPL;
        if constexpr (VPL == 4) {
            const ushort4_t v = *reinterpret_cast<const ushort4_t*>(p);
            acc[0] += bf2f(v.x); acc[1] += bf2f(v.y); acc[2] += bf2f(v.z); acc[3] += bf2f(v.w);
        } else if constexpr (VPL == 2) {
            const ushort2_t v = *reinterpret_cast<const ushort2_t*>(p);
            acc[0] += bf2f(v.x); acc[1] += bf2f(v.y);
        } else {
            acc[0] += bf2f(*p);
        }
    };

    int e = beg;
    for (; e + 8 <= end; e += 8) {
        const int s0 = csr[e],     s1 = csr[e + 1], s2 = csr[e + 2], s3 = csr[e + 3];
        const int s4 = csr[e + 4], s5 = csr[e + 5], s6 = csr[e + 6], s7 = csr[e + 7];
        accum(s0); accum(s1); accum(s2); accum(s3);
        accum(s4); accum(s5); accum(s6); accum(s7);
    }
    for (; e + 4 <= end; e += 4) {
        const int s0 = csr[e], s1 = csr[e + 1], s2 = csr[e + 2], s3 = csr[e + 3];
        accum(s0); accum(s1); accum(s2); accum(s3);
    }
    for (; e < end; ++e) accum(csr[e]);

    const float r = rdeg[node];
    unsigned short* o = out + (size_t)node * D + lane * VPL;
    if constexpr (VPL == 4) {
        ushort4_t v = { f2bf(acc[0] * r), f2bf(acc[1] * r), f2bf(acc[2] * r), f2bf(acc[3] * r) };
        *reinterpret_cast<ushort4_t*>(o) = v;
    } else if constexpr (VPL == 2) {
        ushort2_t v = { f2bf(acc[0] * r), f2bf(acc[1] * r) };
        *reinterpret_cast<ushort2_t*>(o) = v;
    } else {
        *o = f2bf(acc[0] * r);
    }
}

// ---------------- MFMA GEMM (global_load_lds + 2-phase double buffer) ----------
// out[m][f] = sum_k A[m][k]*W[f][k] (+bias[f]) (+addC[m][f]) ; optional ReLU
// A = [A1 | A2] along K (K1 + K2, multiples of BK). W likewise [W1 ; W2].
// Tile: BM=128 x BN (128 or 64), BK=64, 256 threads = 4 waves (2x2 wave grid).
// LDS: linear slots (tid*16B), swizzle folded into GLOBAL src col-group and
// ds_read address: col-group' = kseg ^ (row & 7).
template<int K1, int K2, int F, int BN, bool RELU, bool HASBIAS, bool HASADD, bool OUTBF16>
__global__ __launch_bounds__(256, 2) void mfma_gemm(
    const unsigned short* A1, const unsigned short* A2,
    const unsigned short* __restrict__ W1, const unsigned short* __restrict__ W2,
    const float* __restrict__ bias, const unsigned short* __restrict__ addC,
    void* outp) {

    constexpr int BM = 128, BK = 64;
    constexpr int KA = K1 + K2;
    constexpr int WN = BN / 2;
    constexpr int FM = 4, FN = WN / 16;
    constexpr int BBASE = BM * BK * 2;            // 16384
    constexpr int BUFSZ = (BM + BN) * BK * 2;
    constexpr int B_ITERS = (BN * 8) / 256;

    __shared__ __align__(16) char smem[2][BUFSZ];

    const int tid = threadIdx.x;
    const int l = tid & 63;
    const int w = tid >> 6;
    const int wr = w >> 1, wc = w & 1;
    const int lr = l & 15, lhi = l >> 4;
    const int bm = blockIdx.x * BM;
    const int bn = blockIdx.y * BN;

    f32x4 acc[FM][FN];
#pragma unroll
    for (int i = 0; i < FM; ++i)
#pragma unroll
        for (int j = 0; j < FN; ++j) acc[i][j] = (f32x4){0.f, 0.f, 0.f, 0.f};

    int rowA[FM], rowB[FN];
#pragma unroll
    for (int fm = 0; fm < FM; ++fm) rowA[fm] = wr * 64 + fm * 16 + lr;
#pragma unroll
    for (int fn = 0; fn < FN; ++fn) rowB[fn] = wc * WN + fn * 16 + lr;

    auto stage = [&](int buf, int k0) {
        const bool inR1 = (k0 < K1);
        const unsigned short* Ap = inR1 ? A1 : A2;
        const unsigned short* Wp = inR1 ? W1 : W2;
        const int stride = inR1 ? K1 : K2;
        const int kk0 = inR1 ? k0 : (k0 - K1);
        char* sb = smem[buf];
#pragma unroll
        for (int it = 0; it < 4; ++it) {
            const int s = tid + it * 256;
            const int m = s >> 3, kseg = s & 7;
            int mg = bm + m;
            if (mg >= NN) mg = 0;   // clamp: rows >= NN produce discarded output
            gl16(Ap + (size_t)mg * stride + kk0 + ((kseg ^ (m & 7)) << 3), sb + s * 16);
        }
#pragma unroll
        for (int it = 0; it < B_ITERS; ++it) {
            const int s = tid + it * 256;
            const int f = s >> 3, kseg = s & 7;
            gl16(Wp + (size_t)(bn + f) * stride + kk0 + ((kseg ^ (f & 7)) << 3),
                 sb + BBASE + s * 16);
        }
    };

    stage(0, 0);
    __syncthreads();             // drains prologue stage (vmcnt(0) + barrier)

    int cur = 0;
    for (int k0 = 0; k0 < KA; k0 += BK) {
        if (k0 + BK < KA) stage(cur ^ 1, k0 + BK);   // prefetch flies under MFMA
        const char* sb = smem[cur];
#pragma unroll
        for (int ksub = 0; ksub < 2; ++ksub) {
            const int kb = ksub * 4 + lhi;
            s16x8 a[FM], b[FN];
#pragma unroll
            for (int fm = 0; fm < FM; ++fm)
                a[fm] = *reinterpret_cast<const s16x8*>(
                    sb + rowA[fm] * 128 + ((kb ^ (rowA[fm] & 7)) << 4));
#pragma unroll
            for (int fn = 0; fn < FN; ++fn)
                b[fn] = *reinterpret_cast<const s16x8*>(
                    sb + BBASE + rowB[fn] * 128 + ((kb ^ (rowB[fn] & 7)) << 4));
#pragma unroll
            for (int fm = 0; fm < FM; ++fm)
#pragma unroll
                for (int fn = 0; fn < FN; ++fn)
                    acc[fm][fn] = __builtin_amdgcn_mfma_f32_16x16x32_bf16(
                        a[fm], b[fn], acc[fm][fn], 0, 0, 0);
        }
        __syncthreads();         // drains prefetch; all waves done reading cur
        cur ^= 1;
    }

    // epilogue: C/D layout col = l&15, row = (l>>4)*4 + r
#pragma unroll
    for (int fn = 0; fn < FN; ++fn) {
        const int col = bn + wc * WN + fn * 16 + lr;
        const float bv = HASBIAS ? bias[col] : 0.f;
#pragma unroll
        for (int fm = 0; fm < FM; ++fm) {
#pragma unroll
            for (int r = 0; r < 4; ++r) {
                const int row = bm + wr * 64 + fm * 16 + lhi * 4 + r;
                if (row >= NN) continue;
                float v = acc[fm][fn][r] + bv;
                if (HASADD) v += bf2f(addC[(size_t)row * F + col]);
                if (RELU) v = fmaxf(v, 0.f);
                if (OUTBF16)
                    ((unsigned short*)outp)[(size_t)row * F + col] = f2bf(v);
                else
                    ((float*)outp)[(size_t)row * F + col] = v;
            }
        }
    }
}

extern "C" void kernel_launch(void* const* d_in, const int* in_sizes, int n_in,
                              void* d_out, int out_size, void* d_ws, size_t ws_size,
                              hipStream_t stream) {
    const float* feats = (const float*)d_in[0];
    const int*   esrc  = (const int*)d_in[1];
    const int*   edst  = (const int*)d_in[2];
    const float* W0s = (const float*)d_in[3];
    const float* W0n = (const float*)d_in[4];
    const float* b0  = (const float*)d_in[5];
    const float* W1s = (const float*)d_in[6];
    const float* W1n = (const float*)d_in[7];
    const float* b1  = (const float*)d_in[8];
    const float* W2s = (const float*)d_in[9];
    const float* W2n = (const float*)d_in[10];
    const float* b2  = (const float*)d_in[11];
    float* out = (float*)d_out;

    char* p = (char*)d_ws;
    auto alloc = [&](size_t bytes) { char* r = p; p += (bytes + 255) & ~255ull; return r; };
    int*   degi      = (int*)alloc((size_t)NN * 4);
    int*   row_start = (int*)alloc(((size_t)NN + 1) * 4);
    int*   gcur      = (int*)alloc((size_t)NB * 4);
    int*   csr       = (int*)alloc((size_t)NE * 4);
    int2*  ebuf      = (int2*)alloc((size_t)NE * 8);
    float* rdeg      = (float*)alloc((size_t)NN * 4);
    int*   csum      = (int*)alloc((size_t)NCH * 4);
    int*   coff      = (int*)alloc((size_t)NCH * 4);
    unsigned short* wbuf = (unsigned short*)alloc((size_t)229376 * 2);
    unsigned short* fx   = (unsigned short*)alloc((size_t)NN * 128 * 2);
    unsigned short* agg  = (unsigned short*)alloc((size_t)NN * 256 * 2);
    unsigned short* h1   = (unsigned short*)alloc((size_t)NN * 256 * 2);
    unsigned short* h2   = (unsigned short*)alloc((size_t)NN * 256 * 2);
    unsigned short* z    = agg;
    unsigned short* aggz = agg + (size_t)NN * 64;

    const unsigned short* w0s = wbuf;
    const unsigned short* w0n = wbuf + 32768;
    const unsigned short* w1s = wbuf + 65536;
    const unsigned short* w1n = wbuf + 131072;
    const unsigned short* w2s = wbuf + 196608;
    const unsigned short* w2n = wbuf + 212992;

    // ---- CSR build (parallel scan + two-phase bucketed fill)
    hipMemsetAsync(degi, 0, (size_t)NN * 4, stream);
    deg_hist_kernel<<<(NE + 255) / 256, 256, 0, stream>>>(edst, degi, NE);
    chunk_sum_kernel<<<NCH, 256, 0, stream>>>(degi, csum);
    chunk_scan_kernel<<<1, 128, 0, stream>>>(csum, coff, row_start);
    scan_write_kernel<<<NCH, 256, 0, stream>>>(degi, coff, row_start, gcur, rdeg);
    bucket_scatter_kernel<<<(NE + EPB_A - 1) / EPB_A, 256, 0, stream>>>(esrc, edst, gcur, ebuf);
    bucket_fill_kernel<<<NB, 256, 0, stream>>>(ebuf, row_start, csr);

    // ---- converts
    cvt_f32_bf16<<<(NN * 128 / 4 + 255) / 256, 256, 0, stream>>>(feats, fx, NN * 128 / 4);
    cvt_weights<<<(229376 / 4 + 255) / 256, 256, 0, stream>>>(W0s, W0n, W1s, W1n, W2s, W2n, wbuf);

    const int gather_grid = (NN + 3) / 4;
    const dim3 g256((NN + 127) / 128, 2);
    const dim3 g64((NN + 127) / 128, 1);

    // ---- layer 0: fx[N,128] -> h1[N,256], ReLU
    gather_mean_bf16<128><<<gather_grid, 256, 0, stream>>>(fx, row_start, csr, rdeg, agg);
    mfma_gemm<128, 128, 256, 128, true, true, false, true>
        <<<g256, 256, 0, stream>>>(fx, agg, w0s, w0n, b0, nullptr, h1);

    // ---- layer 1: h1[N,256] -> h2[N,256], ReLU
    gather_mean_bf16<256><<<gather_grid, 256, 0, stream>>>(h1, row_start, csr, rdeg, agg);
    mfma_gemm<256, 256, 256, 128, true, true, false, true>
        <<<g256, 256, 0, stream>>>(h1, agg, w1s, w1n, b1, nullptr, h2);

    // ---- layer 2: transform-before-aggregate
    mfma_gemm<256, 0, 64, 64, false, false, false, true>
        <<<g64, 256, 0, stream>>>(h2, nullptr, w2n, nullptr, nullptr, nullptr, z);
    gather_mean_bf16<64><<<gather_grid, 256, 0, stream>>>(z, row_start, csr, rdeg, aggz);
    mfma_gemm<256, 0, 64, 64, false, true, true, false>
        <<<g64, 256, 0, stream>>>(h2, nullptr, w2s, nullptr, b2, aggz, out);
}

// Round 8
// 554.720 us; speedup vs baseline: 1.1350x; 1.1350x over previous
//
#include <hip/hip_runtime.h>

// GraphSAGE 3-layer. Round 8:
//   (1) CSR build without node-level global atomics: bucket histogram (LDS) ->
//       391-wide scan -> bucket_scatter -> bucket_build (per-node degrees,
//       row_start, rdeg, csr all derived in LDS from bucketed ebuf).
//       Replaces deg_hist (1.6M random global atomics) + 100K-wide scan.
//   (2) gather-mean with 2 nodes/wave (32 lanes/node) for D=256/128 and
//       4 nodes/wave at D=64 -> 2x in-flight bytes (latency-bound regime).
//   GEMM = round-6 known-good (reg-staged swizzled LDS, single buffer).

constexpr int NN = 100000;
constexpr int NE = 1600000;

typedef short s16x8 __attribute__((ext_vector_type(8)));
typedef unsigned short u16x8 __attribute__((ext_vector_type(8)));
typedef float f32x4 __attribute__((ext_vector_type(4)));

struct ushort4_t { unsigned short x, y, z, w; };

__device__ __forceinline__ float bf2f(unsigned short u) {
    union { unsigned int i; float f; } c; c.i = ((unsigned int)u) << 16; return c.f;
}
__device__ __forceinline__ unsigned short f2bf(float f) {
    union { float f; unsigned int i; } c; c.f = f;
    unsigned int r = (c.i + 0x7fffu + ((c.i >> 16) & 1u)) >> 16;
    return (unsigned short)r;
}

constexpr int NB = (NN + 255) / 256;              // 391 dst buckets (256 nodes each)
constexpr int EPB_A = 4096;                       // edges per block (bucket kernels)
constexpr int NBLK_E = (NE + EPB_A - 1) / EPB_A;  // 391

// ---- CSR build ----
__global__ __launch_bounds__(256) void bucket_count_kernel(
    const int* __restrict__ dst, int* __restrict__ bcnt) {
    __shared__ int hist[NB];
    const int blk = blockIdx.x, t = threadIdx.x;
    for (int b = t; b < NB; b += 256) hist[b] = 0;
    __syncthreads();
#pragma unroll
    for (int u = 0; u < 16; ++u) {
        const int i = blk * EPB_A + u * 256 + t;
        if (i < NE) atomicAdd(&hist[dst[i] >> 8], 1);
    }
    __syncthreads();
    for (int b = t; b < NB; b += 256)
        if (hist[b]) atomicAdd(&bcnt[b], hist[b]);
}

__global__ void bucket_scan_kernel(const int* __restrict__ bcnt, int* __restrict__ bbase,
                                   int* __restrict__ gcur, int* __restrict__ row_start) {
    __shared__ int sh[512];
    const int t = threadIdx.x;
    const int v0 = (t < NB) ? bcnt[t] : 0;
    sh[t] = v0;
    __syncthreads();
    for (int o = 1; o < 512; o <<= 1) {
        const int v = (t >= o) ? sh[t - o] : 0;
        __syncthreads();
        sh[t] += v;
        __syncthreads();
    }
    if (t < NB) { const int e = sh[t] - v0; bbase[t] = e; gcur[t] = e; }
    if (t == 0) { bbase[NB] = NE; row_start[NN] = NE; }
}

__global__ __launch_bounds__(256) void bucket_scatter_kernel(
    const int* __restrict__ src, const int* __restrict__ dst,
    int* __restrict__ gcur, int2* __restrict__ ebuf) {
    __shared__ int hist[NB];
    __shared__ int base[NB];
    const int blk = blockIdx.x, t = threadIdx.x;
    int myS[16], myD[16];
#pragma unroll
    for (int u = 0; u < 16; ++u) {
        const int i = blk * EPB_A + u * 256 + t;
        if (i < NE) { myS[u] = src[i]; myD[u] = dst[i]; } else myD[u] = -1;
    }
    for (int b = t; b < NB; b += 256) hist[b] = 0;
    __syncthreads();
#pragma unroll
    for (int u = 0; u < 16; ++u)
        if (myD[u] >= 0) atomicAdd(&hist[myD[u] >> 8], 1);
    __syncthreads();
    for (int b = t; b < NB; b += 256) {
        const int c = hist[b];
        base[b] = c ? atomicAdd(&gcur[b], c) : 0;
    }
    __syncthreads();
    for (int b = t; b < NB; b += 256) hist[b] = 0;
    __syncthreads();
#pragma unroll
    for (int u = 0; u < 16; ++u)
        if (myD[u] >= 0) {
            const int bk = myD[u] >> 8;
            const int off = atomicAdd(&hist[bk], 1);
            ebuf[base[bk] + off] = make_int2(myS[u], myD[u]);
        }
}

// one block per bucket: degrees + local scan + row_start/rdeg + csr fill
__global__ __launch_bounds__(256) void bucket_build_kernel(
    const int2* __restrict__ ebuf, const int* __restrict__ bbase,
    int* __restrict__ row_start, float* __restrict__ rdeg, int* __restrict__ csr) {
    __shared__ int deg[256];
    __shared__ int sh[256];
    __shared__ int lcur[256];
    const int b = blockIdx.x, t = threadIdx.x;
    const int beg = bbase[b], end = bbase[b + 1];
    deg[t] = 0;
    __syncthreads();
    for (int i = beg + t; i < end; i += 256)
        atomicAdd(&deg[ebuf[i].y & 255], 1);
    __syncthreads();
    const int d = deg[t];
    sh[t] = d;
    __syncthreads();
    for (int o = 1; o < 256; o <<= 1) {
        const int v = (t >= o) ? sh[t - o] : 0;
        __syncthreads();
        sh[t] += v;
        __syncthreads();
    }
    const int node = (b << 8) + t;
    const int rs = beg + sh[t] - d;   // exclusive
    if (node < NN) {
        row_start[node] = rs;
        rdeg[node] = 1.0f / (float)max(d, 1);
    }
    lcur[t] = rs;
    __syncthreads();
    for (int i = beg + t; i < end; i += 256) {
        const int2 e = ebuf[i];
        const int p = atomicAdd(&lcur[e.y & 255], 1);
        csr[p] = e.x;
    }
}

// ---- fp32 -> bf16 converts ----
__global__ void cvt_f32_bf16(const float* __restrict__ src, unsigned short* __restrict__ dst, int nquad) {
    int i = blockIdx.x * blockDim.x + threadIdx.x;
    if (i >= nquad) return;
    const float4 v = reinterpret_cast<const float4*>(src)[i];
    ushort4_t o = { f2bf(v.x), f2bf(v.y), f2bf(v.z), f2bf(v.w) };
    reinterpret_cast<ushort4_t*>(dst)[i] = o;
}

__global__ void cvt_weights(const float* a, const float* b, const float* c,
                            const float* d, const float* e, const float* f,
                            unsigned short* __restrict__ o) {
    int i = blockIdx.x * blockDim.x + threadIdx.x;
    int q = i * 4;
    if (q >= 229376) return;
    const float* s; int off;
    if      (q <  32768) { s = a; off = 0; }
    else if (q <  65536) { s = b; off = 32768; }
    else if (q < 131072) { s = c; off = 65536; }
    else if (q < 196608) { s = d; off = 131072; }
    else if (q < 212992) { s = e; off = 196608; }
    else                 { s = f; off = 212992; }
    const float4 v = *reinterpret_cast<const float4*>(s + (q - off));
    ushort4_t ov = { f2bf(v.x), f2bf(v.y), f2bf(v.z), f2bf(v.w) };
    *reinterpret_cast<ushort4_t*>(o + q) = ov;
}

// ---- gather-mean: SUBW lanes per node, BPL bytes per lane ----
template<int D, int SUBW>
__global__ __launch_bounds__(256) void gather_mean_bf16(
    const unsigned short* __restrict__ rows, const int* __restrict__ row_start,
    const int* __restrict__ csr, const float* __restrict__ rdeg,
    unsigned short* __restrict__ out) {
    constexpr int BPL = 2 * D / SUBW;       // 16 (ushort8) or 8 (ushort4)
    constexpr int EPL = BPL / 2;            // elements per lane
    constexpr int NPB = 256 / SUBW;         // nodes per block
    const int sg   = threadIdx.x / SUBW;
    const int lane = threadIdx.x % SUBW;
    const int node = blockIdx.x * NPB + sg;
    if (node >= NN) return;
    const int beg = row_start[node];
    const int end = row_start[node + 1];

    float acc[EPL];
#pragma unroll
    for (int u = 0; u < EPL; ++u) acc[u] = 0.f;

    auto accum = [&](int s) {
        const unsigned short* p = rows + (size_t)s * D + lane * EPL;
        if constexpr (BPL == 16) {
            const u16x8 v = *reinterpret_cast<const u16x8*>(p);
#pragma unroll
            for (int u = 0; u < 8; ++u) acc[u] += bf2f((unsigned short)v[u]);
        } else {
            const ushort4_t v = *reinterpret_cast<const ushort4_t*>(p);
            acc[0] += bf2f(v.x); acc[1] += bf2f(v.y); acc[2] += bf2f(v.z); acc[3] += bf2f(v.w);
        }
    };

    int e = beg;
    for (; e + 8 <= end; e += 8) {
        const int s0 = csr[e],     s1 = csr[e + 1], s2 = csr[e + 2], s3 = csr[e + 3];
        const int s4 = csr[e + 4], s5 = csr[e + 5], s6 = csr[e + 6], s7 = csr[e + 7];
        accum(s0); accum(s1); accum(s2); accum(s3);
        accum(s4); accum(s5); accum(s6); accum(s7);
    }
    for (; e < end; ++e) accum(csr[e]);

    const float r = rdeg[node];
    unsigned short* o = out + (size_t)node * D + lane * EPL;
    if constexpr (BPL == 16) {
        u16x8 v;
#pragma unroll
        for (int u = 0; u < 8; ++u) v[u] = (unsigned short)f2bf(acc[u] * r);
        *reinterpret_cast<u16x8*>(o) = v;
    } else {
        ushort4_t v = { f2bf(acc[0] * r), f2bf(acc[1] * r), f2bf(acc[2] * r), f2bf(acc[3] * r) };
        *reinterpret_cast<ushort4_t*>(o) = v;
    }
}

// ---- MFMA GEMM (round-6 known-good: reg-staged, swizzled LDS, 1 buffer) ----
template<int K1, int K2, int F, int BN, bool RELU, bool HASBIAS, bool HASADD, bool OUTBF16>
__global__ __launch_bounds__(256, 2) void mfma_gemm(
    const unsigned short* A1, const unsigned short* A2,
    const unsigned short* __restrict__ W1, const unsigned short* __restrict__ W2,
    const float* __restrict__ bias, const unsigned short* __restrict__ addC,
    void* outp) {

    constexpr int BM = 128, BK = 64;
    constexpr int KA = K1 + K2;
    constexpr int WN = BN / 2;
    constexpr int FM = 4, FN = WN / 16;
    constexpr int ABASE = 0;
    constexpr int BBASE = BM * BK * 2;
    constexpr int B_ITERS = (BN * 8) / 256;

    __shared__ __align__(16) char smem[(BM + BN) * BK * 2];

    const int tid = threadIdx.x;
    const int l = tid & 63;
    const int w = tid >> 6;
    const int wr = w >> 1, wc = w & 1;
    const int lr = l & 15, lhi = l >> 4;
    const int bm = blockIdx.x * BM;
    const int bn = blockIdx.y * BN;

    f32x4 acc[FM][FN];
#pragma unroll
    for (int i = 0; i < FM; ++i)
#pragma unroll
        for (int j = 0; j < FN; ++j) acc[i][j] = (f32x4){0.f, 0.f, 0.f, 0.f};

    int rowA[FM], rowB[FN];
#pragma unroll
    for (int fm = 0; fm < FM; ++fm) rowA[fm] = wr * 64 + fm * 16 + lr;
#pragma unroll
    for (int fn = 0; fn < FN; ++fn) rowB[fn] = wc * WN + fn * 16 + lr;

    for (int k0 = 0; k0 < KA; k0 += BK) {
        const bool inR1 = (k0 < K1);
        const unsigned short* Ap = inR1 ? A1 : A2;
        const unsigned short* Wp = inR1 ? W1 : W2;
        const int stride = inR1 ? K1 : K2;
        const int kk0 = inR1 ? k0 : (k0 - K1);

#pragma unroll
        for (int it = 0; it < 4; ++it) {
            const int s = tid + it * 256;
            const int m = s >> 3;
            const int kseg = s & 7;
            float4 v = make_float4(0.f, 0.f, 0.f, 0.f);
            const int mg = bm + m;
            if (mg < NN)
                v = *reinterpret_cast<const float4*>(Ap + (size_t)mg * stride + kk0 + kseg * 8);
            *reinterpret_cast<float4*>(smem + ABASE + m * 128 + ((kseg ^ (m & 7)) << 4)) = v;
        }
#pragma unroll
        for (int it = 0; it < B_ITERS; ++it) {
            const int s = tid + it * 256;
            const int f = s >> 3;
            const int kseg = s & 7;
            const float4 v = *reinterpret_cast<const float4*>(
                Wp + (size_t)(bn + f) * stride + kk0 + kseg * 8);
            *reinterpret_cast<float4*>(smem + BBASE + f * 128 + ((kseg ^ (f & 7)) << 4)) = v;
        }
        __syncthreads();

#pragma unroll
        for (int ksub = 0; ksub < 2; ++ksub) {
            const int kb = ksub * 4 + lhi;
            s16x8 a[FM], b[FN];
#pragma unroll
            for (int fm = 0; fm < FM; ++fm)
                a[fm] = *reinterpret_cast<const s16x8*>(
                    smem + ABASE + rowA[fm] * 128 + ((kb ^ (rowA[fm] & 7)) << 4));
#pragma unroll
            for (int fn = 0; fn < FN; ++fn)
                b[fn] = *reinterpret_cast<const s16x8*>(
                    smem + BBASE + rowB[fn] * 128 + ((kb ^ (rowB[fn] & 7)) << 4));
#pragma unroll
            for (int fm = 0; fm < FM; ++fm)
#pragma unroll
                for (int fn = 0; fn < FN; ++fn)
                    acc[fm][fn] = __builtin_amdgcn_mfma_f32_16x16x32_bf16(
                        a[fm], b[fn], acc[fm][fn], 0, 0, 0);
        }
        __syncthreads();
    }

#pragma unroll
    for (int fn = 0; fn < FN; ++fn) {
        const int col = bn + wc * WN + fn * 16 + lr;
        const float bv = HASBIAS ? bias[col] : 0.f;
#pragma unroll
        for (int fm = 0; fm < FM; ++fm) {
#pragma unroll
            for (int r = 0; r < 4; ++r) {
                const int row = bm + wr * 64 + fm * 16 + lhi * 4 + r;
                if (row >= NN) continue;
                float v = acc[fm][fn][r] + bv;
                if (HASADD) v += bf2f(addC[(size_t)row * F + col]);
                if (RELU) v = fmaxf(v, 0.f);
                if (OUTBF16)
                    ((unsigned short*)outp)[(size_t)row * F + col] = f2bf(v);
                else
                    ((float*)outp)[(size_t)row * F + col] = v;
            }
        }
    }
}

extern "C" void kernel_launch(void* const* d_in, const int* in_sizes, int n_in,
                              void* d_out, int out_size, void* d_ws, size_t ws_size,
                              hipStream_t stream) {
    const float* feats = (const float*)d_in[0];
    const int*   esrc  = (const int*)d_in[1];
    const int*   edst  = (const int*)d_in[2];
    const float* W0s = (const float*)d_in[3];
    const float* W0n = (const float*)d_in[4];
    const float* b0  = (const float*)d_in[5];
    const float* W1s = (const float*)d_in[6];
    const float* W1n = (const float*)d_in[7];
    const float* b1  = (const float*)d_in[8];
    const float* W2s = (const float*)d_in[9];
    const float* W2n = (const float*)d_in[10];
    const float* b2  = (const float*)d_in[11];
    float* out = (float*)d_out;

    char* p = (char*)d_ws;
    auto alloc = [&](size_t bytes) { char* r = p; p += (bytes + 255) & ~255ull; return r; };
    int*   row_start = (int*)alloc(((size_t)NN + 1) * 4);
    int*   bcnt      = (int*)alloc((size_t)NB * 4);
    int*   bbase     = (int*)alloc(((size_t)NB + 1) * 4);
    int*   gcur      = (int*)alloc((size_t)NB * 4);
    int*   csr       = (int*)alloc((size_t)NE * 4);
    int2*  ebuf      = (int2*)alloc((size_t)NE * 8);
    float* rdeg      = (float*)alloc((size_t)NN * 4);
    unsigned short* wbuf = (unsigned short*)alloc((size_t)229376 * 2);
    unsigned short* fx   = (unsigned short*)alloc((size_t)NN * 128 * 2);
    unsigned short* agg  = (unsigned short*)alloc((size_t)NN * 256 * 2);
    unsigned short* h1   = (unsigned short*)alloc((size_t)NN * 256 * 2);
    unsigned short* h2   = (unsigned short*)alloc((size_t)NN * 256 * 2);
    unsigned short* z    = agg;
    unsigned short* aggz = agg + (size_t)NN * 64;

    const unsigned short* w0s = wbuf;
    const unsigned short* w0n = wbuf + 32768;
    const unsigned short* w1s = wbuf + 65536;
    const unsigned short* w1n = wbuf + 131072;
    const unsigned short* w2s = wbuf + 196608;
    const unsigned short* w2n = wbuf + 212992;

    // ---- CSR build (bucket-level only; no node-level global atomics)
    hipMemsetAsync(bcnt, 0, (size_t)NB * 4, stream);
    bucket_count_kernel<<<NBLK_E, 256, 0, stream>>>(edst, bcnt);
    bucket_scan_kernel<<<1, 512, 0, stream>>>(bcnt, bbase, gcur, row_start);
    bucket_scatter_kernel<<<NBLK_E, 256, 0, stream>>>(esrc, edst, gcur, ebuf);
    bucket_build_kernel<<<NB, 256, 0, stream>>>(ebuf, bbase, row_start, rdeg, csr);

    // ---- converts
    cvt_f32_bf16<<<(NN * 128 / 4 + 255) / 256, 256, 0, stream>>>(feats, fx, NN * 128 / 4);
    cvt_weights<<<(229376 / 4 + 255) / 256, 256, 0, stream>>>(W0s, W0n, W1s, W1n, W2s, W2n, wbuf);

    const dim3 g256((NN + 127) / 128, 2);
    const dim3 g64((NN + 127) / 128, 1);

    // ---- layer 0: fx[N,128] -> h1[N,256], ReLU
    gather_mean_bf16<128, 32><<<(NN + 7) / 8, 256, 0, stream>>>(fx, row_start, csr, rdeg, agg);
    mfma_gemm<128, 128, 256, 128, true, true, false, true>
        <<<g256, 256, 0, stream>>>(fx, agg, w0s, w0n, b0, nullptr, h1);

    // ---- layer 1: h1[N,256] -> h2[N,256], ReLU
    gather_mean_bf16<256, 32><<<(NN + 7) / 8, 256, 0, stream>>>(h1, row_start, csr, rdeg, agg);
    mfma_gemm<256, 256, 256, 128, true, true, false, true>
        <<<g256, 256, 0, stream>>>(h1, agg, w1s, w1n, b1, nullptr, h2);

    // ---- layer 2: transform-before-aggregate
    mfma_gemm<256, 0, 64, 64, false, false, false, true>
        <<<g64, 256, 0, stream>>>(h2, nullptr, w2n, nullptr, nullptr, nullptr, z);
    gather_mean_bf16<64, 16><<<(NN + 15) / 16, 256, 0, stream>>>(z, row_start, csr, rdeg, aggz);
    mfma_gemm<256, 0, 64, 64, false, true, true, false>
        <<<g64, 256, 0, stream>>>(h2, nullptr, w2s, nullptr, b2, aggz, out);
}